// Round 9
// baseline (141.774 us; speedup 1.0000x reference)
//
#include <hip/hip_runtime.h>
#include <hip/hip_bf16.h>

// MultiHeadAttention: S=2048, B=2, EMB=512, H=8, D=64 -> 16 (b,h) groups of
// [2048 x 64] attention + per-head 64x64 QKV proj + 512x512 output FC.
//
// R9: 32x32x16 flash redone: single chained S accumulator (zero-C hoisted),
// v_cvt_pk_bf16_f32 packing, 72-u16-row K/V tiles (R7-proven bank mixing),
// P buffer 40-u16 rows with qx swizzle (verified min bank occupancy),
// XCD-swizzled 1D grid (g = bi&15; FETCH 35->6MB in R8). proj/fc as R7.
//
// ws: [0)   Qb 32768x64 bf16 (pre-scaled by 0.125*log2e)
//     [4M)  Kb 32768x64 bf16
//     [8M)  Vt [16][64][2048] bf16
//     [12M) At 32768x64 bf16
//     [16M) Wb 512x512 bf16
//     [16M+512K) KnSq[256] float

typedef __attribute__((ext_vector_type(8))) __bf16 bf16x8;
typedef __attribute__((ext_vector_type(4))) float f32x4;
typedef __attribute__((ext_vector_type(16))) float f32x16;
typedef __attribute__((ext_vector_type(4))) unsigned short u16x4;
typedef __attribute__((ext_vector_type(4))) unsigned int u32x4;
typedef unsigned short u16;
typedef unsigned int u32;

static __device__ __forceinline__ u16 f2bf(float x) {
    u32 u = __float_as_uint(x);
    u += 0x7fff + ((u >> 16) & 1);   // RNE
    return (u16)(u >> 16);
}
static __device__ __forceinline__ float bf2f(u16 h) {
    return __uint_as_float(((u32)h) << 16);
}
// packed bf16x2 convert (v_cvt_pk_bf16_f32 on gfx950)
static __device__ __forceinline__ u32 pk2(float lo, float hi) {
    __hip_bfloat162 h2 = __float22bfloat162_rn(make_float2(lo, hi));
    u32 r; __builtin_memcpy(&r, &h2, 4); return r;
}

// ---------------------------------------------------------------------------
// Kernel 1: z=0/1/2 -> QKV projection (Y = X@W^T * scale), z=3 -> Wfc->bf16.
// z=1 (K) additionally writes per-block max row-norm^2 to KnSq[bx].
// ---------------------------------------------------------------------------
__global__ __launch_bounds__(256) void proj_kernel(
    const float* __restrict__ q, const float* __restrict__ k, const float* __restrict__ v,
    const float* __restrict__ Wq, const float* __restrict__ Wk, const float* __restrict__ Wv,
    const float* __restrict__ Wfc,
    u16* __restrict__ Qb, u16* __restrict__ Kb, u16* __restrict__ Vt,
    u16* __restrict__ Wb, float* __restrict__ KnSq)
{
    const int mode = blockIdx.z;
    const int t = threadIdx.x;

    if (mode == 3) {
        int i = (blockIdx.x * 256 + t) * 4;
        float4 val = *(const float4*)(Wfc + i);
        uint2 b = { pk2(val.x, val.y), pk2(val.z, val.w) };
        *(uint2*)(Wb + i) = b;
        return;
    }

    const float* A = (mode == 0) ? q : (mode == 1) ? k : v;
    const float* W = (mode == 0) ? Wq : (mode == 1) ? Wk : Wv;
    const float osc = (mode == 0) ? 0.18033688011112042f : 1.0f; // 0.125*log2(e)

    __shared__ alignas(16) u16 Ash[128 * 88];
    __shared__ alignas(16) u16 Wsh[64 * 88];
    __shared__ float red[128];

    const int m0 = blockIdx.x * 128;
    const int w = t >> 6, l = t & 63;
    const int r16 = l & 15, q4 = l >> 4;

    {
        const float4* A4 = (const float4*)(A + (size_t)m0 * 64);
        const int c4 = t & 15;
        #pragma unroll
        for (int i = 0; i < 8; ++i) {
            int row = (t >> 4) + i * 16;
            float4 val = A4[row * 16 + c4];
            uint2 bb = { pk2(val.x, val.y), pk2(val.z, val.w) };
            *(uint2*)(Ash + row * 88 + c4 * 4) = bb;
        }
        const float4* W4 = (const float4*)W;
        #pragma unroll
        for (int i = 0; i < 4; ++i) {
            int row = (t >> 4) + i * 16;
            float4 val = W4[row * 16 + c4];
            uint2 bb = { pk2(val.x, val.y), pk2(val.z, val.w) };
            *(uint2*)(Wsh + row * 88 + c4 * 4) = bb;
        }
    }
    __syncthreads();

    bf16x8 af[2][2], wf[4][2];
    #pragma unroll
    for (int mc = 0; mc < 2; ++mc)
        #pragma unroll
        for (int kk = 0; kk < 2; ++kk)
            af[mc][kk] = *(const bf16x8*)(Ash + (w * 32 + mc * 16 + r16) * 88 + kk * 32 + q4 * 8);
    #pragma unroll
    for (int nc = 0; nc < 4; ++nc)
        #pragma unroll
        for (int kk = 0; kk < 2; ++kk)
            wf[nc][kk] = *(const bf16x8*)(Wsh + (nc * 16 + r16) * 88 + kk * 32 + q4 * 8);

    f32x4 acc[2][4];
    const f32x4 zero = {0.f, 0.f, 0.f, 0.f};
    #pragma unroll
    for (int mc = 0; mc < 2; ++mc)
        #pragma unroll
        for (int nc = 0; nc < 4; ++nc) {
            acc[mc][nc] = __builtin_amdgcn_mfma_f32_16x16x32_bf16(af[mc][0], wf[nc][0], zero, 0, 0, 0);
            acc[mc][nc] = __builtin_amdgcn_mfma_f32_16x16x32_bf16(af[mc][1], wf[nc][1], acc[mc][nc], 0, 0, 0);
        }

    __syncthreads();

    if (mode < 2) {
        #pragma unroll
        for (int mc = 0; mc < 2; ++mc)
            #pragma unroll
            for (int nc = 0; nc < 4; ++nc)
                #pragma unroll
                for (int r = 0; r < 4; ++r)
                    Ash[(w * 32 + mc * 16 + q4 * 4 + r) * 72 + nc * 16 + r16] = f2bf(acc[mc][nc][r] * osc);
        __syncthreads();
        u16* Out = ((mode == 0) ? Qb : Kb) + (size_t)m0 * 64;
        {
            int row = t >> 1, cbase = (t & 1) * 32;
            #pragma unroll
            for (int i = 0; i < 4; ++i)
                *(u32x4*)(Out + row * 64 + cbase + i * 8) = *(const u32x4*)(Ash + row * 72 + cbase + i * 8);
        }
        if (mode == 1) {
            if (t < 128) {
                float ss = 0.f;
                #pragma unroll
                for (int c = 0; c < 8; ++c) {
                    u32x4 d = *(const u32x4*)(Ash + t * 72 + c * 8);
                    #pragma unroll
                    for (int j = 0; j < 4; ++j) {
                        float lo = bf2f((u16)(d[j] & 0xffff));
                        float hi = bf2f((u16)(d[j] >> 16));
                        ss += lo * lo + hi * hi;
                    }
                }
                red[t] = ss;
            }
            __syncthreads();
            if (t < 64) red[t] = fmaxf(red[t], red[t + 64]);
            __syncthreads();
            if (t < 32) red[t] = fmaxf(red[t], red[t + 32]);
            __syncthreads();
            if (t == 0) {
                float mx = red[0];
                for (int i = 1; i < 32; ++i) mx = fmaxf(mx, red[i]);
                KnSq[blockIdx.x] = mx;
            }
        }
    } else {
        #pragma unroll
        for (int mc = 0; mc < 2; ++mc)
            #pragma unroll
            for (int nc = 0; nc < 4; ++nc)
                #pragma unroll
                for (int r = 0; r < 4; ++r)
                    Ash[(nc * 16 + r16) * 136 + w * 32 + mc * 16 + q4 * 4 + r] = f2bf(acc[mc][nc][r]);
        __syncthreads();
        const int g = m0 >> 11, s0 = m0 & 2047;
        int d = t >> 2, sb = (t & 3) * 32;
        u16* Out = Vt + ((size_t)(g * 64 + d)) * 2048 + s0;
        #pragma unroll
        for (int i = 0; i < 4; ++i)
            *(u32x4*)(Out + sb + i * 8) = *(const u32x4*)(Ash + d * 136 + sb + i * 8);
    }
}

// ---------------------------------------------------------------------------
// Kernel 2: flash attention on 32x32x16 MFMA, v2.
// Block = 4 waves = (q-chunk qs x key-half kh); 64 q x 2048 keys; 64-key
// double-buffered LDS tiles (72-u16 rows, ck^(row&7) chunk swizzle).
// Fixed softmax bound; single chained S accumulator; pk-bf16 packing.
// P buffer: per-wave [32 q][40 u16], chunk swizzle qx = (q5&3)^((q5>>3)&3).
// A/B frag: m|n = lane&31, k = (lane>>5)*8+j.
// C/D: col = lane&31, row = (reg&3)+8*(reg>>2)+4*(lane>>5).
// ---------------------------------------------------------------------------
__global__ __launch_bounds__(256) void flash_kernel(
    const u16* __restrict__ Qb, const u16* __restrict__ Kb,
    const u16* __restrict__ Vt, const float* __restrict__ KnSq,
    u16* __restrict__ Att)
{
    const int bi = blockIdx.x;
    const int g = bi & 15;        // XCD co-location
    const int qt = bi >> 4;       // 0..31
    const int t = threadIdx.x, w = t >> 6, l = t & 63;
    const int q5 = l & 31, h = l >> 5;
    const int qs = w >> 1, kh = w & 1;

    // byte layout: KT0 [0,9216) KT1 [9216,18432) VS0 [18432,27648)
    // VS1 [27648,36864) Pw [36864,47104).
    // epilogue overlay: Fsh [0,16896) LsF [16896,17408) Osh [18432,27648).
    __shared__ alignas(16) unsigned char smem[47104];
    u16* const base16 = (u16*)smem;
    u16* const KT0 = base16;
    u16* const KT1 = base16 + 4608;
    u16* const VS0 = base16 + 9216;
    u16* const VS1 = base16 + 13824;
    u16* const PwB = base16 + 18432 + w * 1280;   // [32 q][40 u16]

    const u16* Kg = Kb + ((size_t)g) * 2048 * 64;
    const u16* Vg = Vt + ((size_t)g) * 64 * 2048;

    // Q B-frags: lane n=q5, k = s*16 + h*8 + j
    bf16x8 qb[4];
    {
        const u16* qp = Qb + ((size_t)(g * 2048 + qt * 64 + qs * 32 + q5)) * 64;
        #pragma unroll
        for (int s = 0; s < 4; ++s)
            qb[s] = *(const bf16x8*)(qp + s * 16 + h * 8);
    }

    // fixed bound m = ||Qrow_scaled|| * max||K|| * margin
    float m;
    {
        float kss = KnSq[g * 16 + (l & 15)];
        kss = fmaxf(kss, __shfl_xor(kss, 1));
        kss = fmaxf(kss, __shfl_xor(kss, 2));
        kss = fmaxf(kss, __shfl_xor(kss, 4));
        kss = fmaxf(kss, __shfl_xor(kss, 8));
        float ss = 0.f;
        #pragma unroll
        for (int s = 0; s < 4; ++s)
            #pragma unroll
            for (int j = 0; j < 8; ++j) {
                float x = (float)qb[s][j];
                ss += x * x;
            }
        ss += __shfl_xor(ss, 32);
        m = sqrtf(ss * kss) * 1.0002f;
    }

    // staging: thread t -> rows rr, rr+32; global chunk ck; LDS chunk ck^(rr&7)
    const int rr = t >> 3, ck = t & 7;
    const int sw = (ck ^ (rr & 7)) * 8;

    {   // tile 0 -> buf 0
        #pragma unroll
        for (int h2 = 0; h2 < 2; ++h2) {
            int row = h2 * 32 + rr;
            *(u32x4*)(KT0 + row * 72 + sw) = *(const u32x4*)(Kg + (size_t)row * 64 + ck * 8);
            *(u32x4*)(VS0 + row * 72 + sw) = *(const u32x4*)(Vg + (size_t)row * 2048 + ck * 8);
        }
    }
    __syncthreads();

    f32x16 z16;
    #pragma unroll
    for (int r = 0; r < 16; ++r) z16[r] = 0.f;
    f32x16 o0 = z16, o1 = z16;
    float psum = 0.f;

    const int rk = kh * 32 + q5;          // K-tile row
    const int r7 = q5 & 7;                // row&7 for rk, q5, q5+32
    const int qx = (q5 & 3) ^ ((q5 >> 3) & 3);
    // loop-invariant P addresses
    u16* const pwRow = PwB + q5 * 40;
    const int pvc0 = 4 * kh + h;          // V chunk, s2=0
    const int pvc1 = 4 * kh + 2 + h;      // V chunk, s2=1

    for (int it = 0; it < 32; ++it) {
        u16* const KTc = (it & 1) ? KT1 : KT0;
        u16* const VSc = (it & 1) ? VS1 : VS0;
        u16* const KTn = (it & 1) ? KT0 : KT1;
        u16* const VSn = (it & 1) ? VS0 : VS1;
        const bool hasn = (it < 31);

        u32x4 knx[2], vnx[2];
        if (hasn) {
            #pragma unroll
            for (int h2 = 0; h2 < 2; ++h2) {
                int row = h2 * 32 + rr;
                knx[h2] = *(const u32x4*)(Kg + (size_t)((it + 1) * 64 + row) * 64 + ck * 8);
                vnx[h2] = *(const u32x4*)(Vg + (size_t)row * 2048 + (it + 1) * 64 + ck * 8);
            }
        }

        // QK: chained single accumulator over 4 k-steps (d = 0..63)
        bf16x8 ka0 = *(const bf16x8*)(KTc + rk * 72 + (((0 + h) ^ r7) * 8));
        bf16x8 ka1 = *(const bf16x8*)(KTc + rk * 72 + (((2 + h) ^ r7) * 8));
        bf16x8 ka2 = *(const bf16x8*)(KTc + rk * 72 + (((4 + h) ^ r7) * 8));
        bf16x8 ka3 = *(const bf16x8*)(KTc + rk * 72 + (((6 + h) ^ r7) * 8));
        f32x16 s;
        s = __builtin_amdgcn_mfma_f32_32x32x16_bf16(ka0, qb[0], z16, 0, 0, 0);
        s = __builtin_amdgcn_mfma_f32_32x32x16_bf16(ka1, qb[1], s, 0, 0, 0);
        s = __builtin_amdgcn_mfma_f32_32x32x16_bf16(ka2, qb[2], s, 0, 0, 0);
        s = __builtin_amdgcn_mfma_f32_32x32x16_bf16(ka3, qb[3], s, 0, 0, 0);

        // p = exp2(s - m); per-lane psum
        float p[16];
        float ps = 0.f;
        #pragma unroll
        for (int r = 0; r < 16; ++r) {
            p[r] = exp2f(s[r] - m);
            ps += p[r];
        }
        psum += ps;

        // P^T -> per-wave LDS: regs 4u..4u+3 -> keys 8u+4h+0..3 (uint2, swizzled)
        #pragma unroll
        for (int u = 0; u < 4; ++u) {
            uint2 dd = { pk2(p[4 * u + 0], p[4 * u + 1]),
                         pk2(p[4 * u + 2], p[4 * u + 3]) };
            *(uint2*)(pwRow + ((u ^ qx) * 8) + 4 * h) = dd;
        }
        bf16x8 pb0 = *(const bf16x8*)(pwRow + (((0 + h) ^ qx) * 8));
        bf16x8 pb1 = *(const bf16x8*)(pwRow + (((2 + h) ^ qx) * 8));

        // PV: O^T[d][q] += V^T . P^T  (this wave's 32-key half)
        {
            bf16x8 va0 = *(const bf16x8*)(VSc + q5 * 72 + ((pvc0 ^ r7) * 8));
            bf16x8 va1 = *(const bf16x8*)(VSc + q5 * 72 + ((pvc1 ^ r7) * 8));
            o0 = __builtin_amdgcn_mfma_f32_32x32x16_bf16(va0, pb0, o0, 0, 0, 0);
            o0 = __builtin_amdgcn_mfma_f32_32x32x16_bf16(va1, pb1, o0, 0, 0, 0);
        }
        {
            bf16x8 va0 = *(const bf16x8*)(VSc + (32 + q5) * 72 + ((pvc0 ^ r7) * 8));
            bf16x8 va1 = *(const bf16x8*)(VSc + (32 + q5) * 72 + ((pvc1 ^ r7) * 8));
            o1 = __builtin_amdgcn_mfma_f32_32x32x16_bf16(va0, pb0, o1, 0, 0, 0);
            o1 = __builtin_amdgcn_mfma_f32_32x32x16_bf16(va1, pb1, o1, 0, 0, 0);
        }

        if (hasn) {
            #pragma unroll
            for (int h2 = 0; h2 < 2; ++h2) {
                int row = h2 * 32 + rr;
                *(u32x4*)(KTn + row * 72 + sw) = knx[h2];
                *(u32x4*)(VSn + row * 72 + sw) = vnx[h2];
            }
        }
        __syncthreads();
    }

    // ---- epilogue: merge key-halves, normalize, coalesced store ----
    float psq = psum + __shfl_xor(psum, 32);

    float* const Fsh = (float*)smem;                    // [2 qs][64 lanes][33]
    float* const LsF = (float*)(smem + 16896);          // [2 qs][64 lanes]
    u16*  const Osh = (u16*)(smem + 18432);             // [64 q][72]

    if (kh == 1) {
        float* fp = Fsh + (qs * 64 + l) * 33;
        #pragma unroll
        for (int r = 0; r < 16; ++r) { fp[r] = o0[r]; fp[16 + r] = o1[r]; }
        fp[32] = psq;
        LsF[qs * 64 + l] = psq;
    }
    __syncthreads();
    if (kh == 0) {
        const float* fp = Fsh + (qs * 64 + l) * 33;
        float inv = 1.0f / (psq + LsF[qs * 64 + l]);
        const int qloc = qs * 32 + q5;
        #pragma unroll
        for (int u = 0; u < 4; ++u) {
            uint2 b0 = { pk2((o0[4*u+0] + fp[4*u+0]) * inv, (o0[4*u+1] + fp[4*u+1]) * inv),
                         pk2((o0[4*u+2] + fp[4*u+2]) * inv, (o0[4*u+3] + fp[4*u+3]) * inv) };
            *(uint2*)(Osh + qloc * 72 + 8 * u + 4 * h) = b0;
            uint2 b1 = { pk2((o1[4*u+0] + fp[16+4*u+0]) * inv, (o1[4*u+1] + fp[16+4*u+1]) * inv),
                         pk2((o1[4*u+2] + fp[16+4*u+2]) * inv, (o1[4*u+3] + fp[16+4*u+3]) * inv) };
            *(uint2*)(Osh + qloc * 72 + 32 + 8 * u + 4 * h) = b1;
        }
    }
    __syncthreads();
    {   // coalesced copy Osh -> Att
        int row = t >> 2, cb = (t & 3) * 16;
        u16* dst = Att + ((size_t)(g * 2048 + qt * 64 + row)) * 64 + cb;
        *(u32x4*)(dst)     = *(const u32x4*)(Osh + row * 72 + cb);
        *(u32x4*)(dst + 8) = *(const u32x4*)(Osh + row * 72 + cb + 8);
    }
}

// ---------------------------------------------------------------------------
// Kernel 3: out = Att @ Wb^T + bfc (Wb bf16).  Double-buffered coalesced LDS
// staging, XOR-swizzled fragment reads.  BM=64, BN=64, BK=64; grid (64,8).
// ---------------------------------------------------------------------------
__global__ __launch_bounds__(256) void fc_kernel(
    const u16* __restrict__ Att, const u16* __restrict__ Wb,
    const float* __restrict__ bfc, float* __restrict__ out)
{
    __shared__ alignas(16) u16 Ash[2][64 * 64];
    __shared__ alignas(16) u16 Wsh[2][64 * 64];

    const int t = threadIdx.x, w = t >> 6, l = t & 63;
    const int r16 = l & 15, q4 = l >> 4;
    const int r7 = r16 & 7;
    const int m0 = blockIdx.x * 64, n0 = blockIdx.y * 64;

    const int rr = t >> 3, ck = t & 7;
    const int sw0 = (ck ^ (rr & 7)) * 8;
    const int fr0 = (q4 ^ r7) * 8;
    const int fr1 = ((q4 + 4) ^ r7) * 8;

    {
        #pragma unroll
        for (int h = 0; h < 2; ++h) {
            int row = h * 32 + rr;
            *(u32x4*)(&Ash[0][row * 64 + sw0]) = *(const u32x4*)(Att + (size_t)(m0 + row) * 512 + ck * 8);
            *(u32x4*)(&Wsh[0][row * 64 + sw0]) = *(const u32x4*)(Wb + (size_t)(n0 + row) * 512 + ck * 8);
        }
    }
    __syncthreads();

    f32x4 acc[4];
    const f32x4 zero = {0.f, 0.f, 0.f, 0.f};
    #pragma unroll
    for (int nc = 0; nc < 4; ++nc) acc[nc] = zero;

    for (int it = 0; it < 8; ++it) {
        const int cur = it & 1;
        const bool hasn = (it < 7);

        u32x4 anx[2], wnx[2];
        if (hasn) {
            #pragma unroll
            for (int h = 0; h < 2; ++h) {
                int row = h * 32 + rr;
                anx[h] = *(const u32x4*)(Att + (size_t)(m0 + row) * 512 + (it + 1) * 64 + ck * 8);
                wnx[h] = *(const u32x4*)(Wb + (size_t)(n0 + row) * 512 + (it + 1) * 64 + ck * 8);
            }
        }

        bf16x8 af[2], wf[4][2];
        af[0] = *(const bf16x8*)(&Ash[cur][(w * 16 + r16) * 64 + fr0]);
        af[1] = *(const bf16x8*)(&Ash[cur][(w * 16 + r16) * 64 + fr1]);
        #pragma unroll
        for (int nc = 0; nc < 4; ++nc) {
            wf[nc][0] = *(const bf16x8*)(&Wsh[cur][(nc * 16 + r16) * 64 + fr0]);
            wf[nc][1] = *(const bf16x8*)(&Wsh[cur][(nc * 16 + r16) * 64 + fr1]);
        }

        #pragma unroll
        for (int nc = 0; nc < 4; ++nc) {
            acc[nc] = __builtin_amdgcn_mfma_f32_16x16x32_bf16(af[0], wf[nc][0], acc[nc], 0, 0, 0);
            acc[nc] = __builtin_amdgcn_mfma_f32_16x16x32_bf16(af[1], wf[nc][1], acc[nc], 0, 0, 0);
        }

        if (hasn) {
            const int nxt = cur ^ 1;
            #pragma unroll
            for (int h = 0; h < 2; ++h) {
                int row = h * 32 + rr;
                *(u32x4*)(&Ash[nxt][row * 64 + sw0]) = anx[h];
                *(u32x4*)(&Wsh[nxt][row * 64 + sw0]) = wnx[h];
            }
        }
        __syncthreads();
    }

    #pragma unroll
    for (int nc = 0; nc < 4; ++nc) {
        float bb = bfc[n0 + nc * 16 + r16];
        #pragma unroll
        for (int r = 0; r < 4; ++r) {
            int row = m0 + w * 16 + q4 * 4 + r;
            out[(size_t)row * 512 + n0 + nc * 16 + r16] = acc[nc][r] + bb;
        }
    }
}

extern "C" void kernel_launch(void* const* d_in, const int* in_sizes, int n_in,
                              void* d_out, int out_size, void* d_ws, size_t ws_size,
                              hipStream_t stream) {
    (void)in_sizes; (void)n_in; (void)out_size; (void)ws_size;
    const float* q   = (const float*)d_in[0];
    const float* k   = (const float*)d_in[1];
    const float* v   = (const float*)d_in[2];
    const float* Wq  = (const float*)d_in[3];
    const float* Wk  = (const float*)d_in[4];
    const float* Wv  = (const float*)d_in[5];
    const float* Wfc = (const float*)d_in[6];
    const float* bfc = (const float*)d_in[7];
    float* out = (float*)d_out;

    u16* Qb = (u16*)d_ws;
    u16* Kb = Qb + 2097152;
    u16* Vt = Kb + 2097152;
    u16* At = Vt + 2097152;
    u16* Wb = At + 2097152;
    float* KnSq = (float*)((char*)d_ws + 17301504);

    proj_kernel<<<dim3(256, 1, 4), 256, 0, stream>>>(q, k, v, Wq, Wk, Wv, Wfc,
                                                     Qb, Kb, Vt, Wb, KnSq);
    flash_kernel<<<dim3(512), 256, 0, stream>>>(Qb, Kb, Vt, KnSq, At);
    fc_kernel<<<dim3(64, 8), 256, 0, stream>>>(At, Wb, bfc, out);
}

// Round 10
// 138.264 us; speedup vs baseline: 1.0254x; 1.0254x over previous
//
#include <hip/hip_runtime.h>
#include <hip/hip_bf16.h>

// MultiHeadAttention: S=2048, B=2, EMB=512, H=8, D=64 -> 16 (b,h) groups of
// [2048 x 64] attention + per-head 64x64 QKV proj + 512x512 output FC.
//
// R10: 32x32x16 flash with phase-correct LDS banking. HW model (R7-R9 data):
// wave b128 = 8-lane phases; conflict-free iff each 8 consecutive lanes'
// 16B chunks start at distinct banks {0,4,..,28}. K/V: 64-u16 rows +
// ck^(row&7) (R7-proven). P: 40-u16 rows (stride 20 words, gcd=4 -> row-
// driven rotation), no XOR. Single chained S acc, pk2 packing, fixed bound.
//
// ws: [0)   Qb 32768x64 bf16 (pre-scaled by 0.125*log2e)
//     [4M)  Kb 32768x64 bf16
//     [8M)  Vt [16][64][2048] bf16
//     [12M) At 32768x64 bf16
//     [16M) Wb 512x512 bf16
//     [16M+512K) KnSq[256] float

typedef __attribute__((ext_vector_type(8))) __bf16 bf16x8;
typedef __attribute__((ext_vector_type(4))) float f32x4;
typedef __attribute__((ext_vector_type(16))) float f32x16;
typedef __attribute__((ext_vector_type(4))) unsigned short u16x4;
typedef __attribute__((ext_vector_type(4))) unsigned int u32x4;
typedef unsigned short u16;
typedef unsigned int u32;

static __device__ __forceinline__ u16 f2bf(float x) {
    u32 u = __float_as_uint(x);
    u += 0x7fff + ((u >> 16) & 1);   // RNE
    return (u16)(u >> 16);
}
static __device__ __forceinline__ float bf2f(u16 h) {
    return __uint_as_float(((u32)h) << 16);
}
// packed bf16x2 convert (v_cvt_pk_bf16_f32 on gfx950)
static __device__ __forceinline__ u32 pk2(float lo, float hi) {
    __hip_bfloat162 h2 = __float22bfloat162_rn(make_float2(lo, hi));
    u32 r; __builtin_memcpy(&r, &h2, 4); return r;
}

// ---------------------------------------------------------------------------
// Kernel 1: z=0/1/2 -> QKV projection (Y = X@W^T * scale), z=3 -> Wfc->bf16.
// z=1 (K) additionally writes per-block max row-norm^2 to KnSq[bx].
// ---------------------------------------------------------------------------
__global__ __launch_bounds__(256) void proj_kernel(
    const float* __restrict__ q, const float* __restrict__ k, const float* __restrict__ v,
    const float* __restrict__ Wq, const float* __restrict__ Wk, const float* __restrict__ Wv,
    const float* __restrict__ Wfc,
    u16* __restrict__ Qb, u16* __restrict__ Kb, u16* __restrict__ Vt,
    u16* __restrict__ Wb, float* __restrict__ KnSq)
{
    const int mode = blockIdx.z;
    const int t = threadIdx.x;

    if (mode == 3) {
        int i = (blockIdx.x * 256 + t) * 4;
        float4 val = *(const float4*)(Wfc + i);
        uint2 b = { pk2(val.x, val.y), pk2(val.z, val.w) };
        *(uint2*)(Wb + i) = b;
        return;
    }

    const float* A = (mode == 0) ? q : (mode == 1) ? k : v;
    const float* W = (mode == 0) ? Wq : (mode == 1) ? Wk : Wv;
    const float osc = (mode == 0) ? 0.18033688011112042f : 1.0f; // 0.125*log2(e)

    __shared__ alignas(16) u16 Ash[128 * 88];
    __shared__ alignas(16) u16 Wsh[64 * 88];
    __shared__ float red[128];

    const int m0 = blockIdx.x * 128;
    const int w = t >> 6, l = t & 63;
    const int r16 = l & 15, q4 = l >> 4;

    {
        const float4* A4 = (const float4*)(A + (size_t)m0 * 64);
        const int c4 = t & 15;
        #pragma unroll
        for (int i = 0; i < 8; ++i) {
            int row = (t >> 4) + i * 16;
            float4 val = A4[row * 16 + c4];
            uint2 bb = { pk2(val.x, val.y), pk2(val.z, val.w) };
            *(uint2*)(Ash + row * 88 + c4 * 4) = bb;
        }
        const float4* W4 = (const float4*)W;
        #pragma unroll
        for (int i = 0; i < 4; ++i) {
            int row = (t >> 4) + i * 16;
            float4 val = W4[row * 16 + c4];
            uint2 bb = { pk2(val.x, val.y), pk2(val.z, val.w) };
            *(uint2*)(Wsh + row * 88 + c4 * 4) = bb;
        }
    }
    __syncthreads();

    bf16x8 af[2][2], wf[4][2];
    #pragma unroll
    for (int mc = 0; mc < 2; ++mc)
        #pragma unroll
        for (int kk = 0; kk < 2; ++kk)
            af[mc][kk] = *(const bf16x8*)(Ash + (w * 32 + mc * 16 + r16) * 88 + kk * 32 + q4 * 8);
    #pragma unroll
    for (int nc = 0; nc < 4; ++nc)
        #pragma unroll
        for (int kk = 0; kk < 2; ++kk)
            wf[nc][kk] = *(const bf16x8*)(Wsh + (nc * 16 + r16) * 88 + kk * 32 + q4 * 8);

    f32x4 acc[2][4];
    const f32x4 zero = {0.f, 0.f, 0.f, 0.f};
    #pragma unroll
    for (int mc = 0; mc < 2; ++mc)
        #pragma unroll
        for (int nc = 0; nc < 4; ++nc) {
            acc[mc][nc] = __builtin_amdgcn_mfma_f32_16x16x32_bf16(af[mc][0], wf[nc][0], zero, 0, 0, 0);
            acc[mc][nc] = __builtin_amdgcn_mfma_f32_16x16x32_bf16(af[mc][1], wf[nc][1], acc[mc][nc], 0, 0, 0);
        }

    __syncthreads();

    if (mode < 2) {
        #pragma unroll
        for (int mc = 0; mc < 2; ++mc)
            #pragma unroll
            for (int nc = 0; nc < 4; ++nc)
                #pragma unroll
                for (int r = 0; r < 4; ++r)
                    Ash[(w * 32 + mc * 16 + q4 * 4 + r) * 72 + nc * 16 + r16] = f2bf(acc[mc][nc][r] * osc);
        __syncthreads();
        u16* Out = ((mode == 0) ? Qb : Kb) + (size_t)m0 * 64;
        {
            int row = t >> 1, cbase = (t & 1) * 32;
            #pragma unroll
            for (int i = 0; i < 4; ++i)
                *(u32x4*)(Out + row * 64 + cbase + i * 8) = *(const u32x4*)(Ash + row * 72 + cbase + i * 8);
        }
        if (mode == 1) {
            if (t < 128) {
                float ss = 0.f;
                #pragma unroll
                for (int c = 0; c < 8; ++c) {
                    u32x4 d = *(const u32x4*)(Ash + t * 72 + c * 8);
                    #pragma unroll
                    for (int j = 0; j < 4; ++j) {
                        float lo = bf2f((u16)(d[j] & 0xffff));
                        float hi = bf2f((u16)(d[j] >> 16));
                        ss += lo * lo + hi * hi;
                    }
                }
                red[t] = ss;
            }
            __syncthreads();
            if (t < 64) red[t] = fmaxf(red[t], red[t + 64]);
            __syncthreads();
            if (t < 32) red[t] = fmaxf(red[t], red[t + 32]);
            __syncthreads();
            if (t == 0) {
                float mx = red[0];
                for (int i = 1; i < 32; ++i) mx = fmaxf(mx, red[i]);
                KnSq[blockIdx.x] = mx;
            }
        }
    } else {
        #pragma unroll
        for (int mc = 0; mc < 2; ++mc)
            #pragma unroll
            for (int nc = 0; nc < 4; ++nc)
                #pragma unroll
                for (int r = 0; r < 4; ++r)
                    Ash[(nc * 16 + r16) * 136 + w * 32 + mc * 16 + q4 * 4 + r] = f2bf(acc[mc][nc][r]);
        __syncthreads();
        const int g = m0 >> 11, s0 = m0 & 2047;
        int d = t >> 2, sb = (t & 3) * 32;
        u16* Out = Vt + ((size_t)(g * 64 + d)) * 2048 + s0;
        #pragma unroll
        for (int i = 0; i < 4; ++i)
            *(u32x4*)(Out + sb + i * 8) = *(const u32x4*)(Ash + d * 136 + sb + i * 8);
    }
}

// ---------------------------------------------------------------------------
// Kernel 2: flash attention on 32x32x16 MFMA, v3 (phase-correct banks).
// Block = 4 waves = (q-chunk qs x key-half kh); 64 q x 2048 keys; 64-key
// double-buffered LDS tiles (64-u16 rows, ck^(row&7) chunk swizzle).
// P buffer per wave [32 q][40 u16], no XOR (stride-20-word rotation).
// A/B frag: m|n = lane&31, k = (lane>>5)*8+j.
// C/D: col = lane&31, row = (reg&3)+8*(reg>>2)+4*(lane>>5).
// ---------------------------------------------------------------------------
__global__ __launch_bounds__(256) void flash_kernel(
    const u16* __restrict__ Qb, const u16* __restrict__ Kb,
    const u16* __restrict__ Vt, const float* __restrict__ KnSq,
    u16* __restrict__ Att)
{
    const int bi = blockIdx.x;
    const int g = bi & 15;        // XCD co-location
    const int qt = bi >> 4;       // 0..31
    const int t = threadIdx.x, w = t >> 6, l = t & 63;
    const int q5 = l & 31, h = l >> 5;
    const int qs = w >> 1, kh = w & 1;

    // loop layout (bytes): KT0 [0,8192) KT1 [8192,16384) VS0 [16384,24576)
    // VS1 [24576,32768) P [32768,43008).
    // epilogue overlay: Fsh [0,16896) LsF [16896,17408) Osh [18432,27648).
    __shared__ alignas(16) unsigned char smem[43008];
    u16* const base16 = (u16*)smem;
    u16* const KT0 = base16;
    u16* const KT1 = base16 + 4096;
    u16* const VS0 = base16 + 8192;
    u16* const VS1 = base16 + 12288;
    u16* const PwB = base16 + 16384 + w * 1280;   // [32 q][40 u16]

    const u16* Kg = Kb + ((size_t)g) * 2048 * 64;
    const u16* Vg = Vt + ((size_t)g) * 64 * 2048;

    // Q B-frags: lane n=q5, k = s*16 + h*8 + j
    bf16x8 qb[4];
    {
        const u16* qp = Qb + ((size_t)(g * 2048 + qt * 64 + qs * 32 + q5)) * 64;
        #pragma unroll
        for (int s = 0; s < 4; ++s)
            qb[s] = *(const bf16x8*)(qp + s * 16 + h * 8);
    }

    // fixed bound m = ||Qrow_scaled|| * max||K|| * margin
    float m;
    {
        float kss = KnSq[g * 16 + (l & 15)];
        kss = fmaxf(kss, __shfl_xor(kss, 1));
        kss = fmaxf(kss, __shfl_xor(kss, 2));
        kss = fmaxf(kss, __shfl_xor(kss, 4));
        kss = fmaxf(kss, __shfl_xor(kss, 8));
        float ss = 0.f;
        #pragma unroll
        for (int s = 0; s < 4; ++s)
            #pragma unroll
            for (int j = 0; j < 8; ++j) {
                float x = (float)qb[s][j];
                ss += x * x;
            }
        ss += __shfl_xor(ss, 32);
        m = sqrtf(ss * kss) * 1.0002f;
    }

    // staging: thread t -> rows rr, rr+32; global chunk ck; LDS chunk ck^(rr&7)
    const int rr = t >> 3, ck = t & 7;
    const int sw = (ck ^ (rr & 7)) * 8;

    {   // tile 0 -> buf 0
        #pragma unroll
        for (int h2 = 0; h2 < 2; ++h2) {
            int row = h2 * 32 + rr;
            *(u32x4*)(KT0 + row * 64 + sw) = *(const u32x4*)(Kg + (size_t)row * 64 + ck * 8);
            *(u32x4*)(VS0 + row * 64 + sw) = *(const u32x4*)(Vg + (size_t)row * 2048 + ck * 8);
        }
    }
    __syncthreads();

    f32x16 z16;
    #pragma unroll
    for (int r = 0; r < 16; ++r) z16[r] = 0.f;
    f32x16 o0 = z16, o1 = z16;
    float psum = 0.f;

    const int rk = kh * 32 + q5;          // K-tile row
    const int r7 = q5 & 7;                // row&7 for rk, q5, 32+q5
    u16* const pwRow = PwB + q5 * 40;
    const int vc0 = 4 * kh + h;           // V k-chunk, s2=0
    const int vc1 = 4 * kh + 2 + h;       // V k-chunk, s2=1

    for (int it = 0; it < 32; ++it) {
        u16* const KTc = (it & 1) ? KT1 : KT0;
        u16* const VSc = (it & 1) ? VS1 : VS0;
        u16* const KTn = (it & 1) ? KT0 : KT1;
        u16* const VSn = (it & 1) ? VS0 : VS1;
        const bool hasn = (it < 31);

        u32x4 knx[2], vnx[2];
        if (hasn) {
            #pragma unroll
            for (int h2 = 0; h2 < 2; ++h2) {
                int row = h2 * 32 + rr;
                knx[h2] = *(const u32x4*)(Kg + (size_t)((it + 1) * 64 + row) * 64 + ck * 8);
                vnx[h2] = *(const u32x4*)(Vg + (size_t)row * 2048 + (it + 1) * 64 + ck * 8);
            }
        }

        // QK: chained single accumulator over 4 k-steps (k-chunk = 2s+h)
        bf16x8 ka0 = *(const bf16x8*)(KTc + rk * 64 + (((0 + h) ^ r7) * 8));
        bf16x8 ka1 = *(const bf16x8*)(KTc + rk * 64 + (((2 + h) ^ r7) * 8));
        bf16x8 ka2 = *(const bf16x8*)(KTc + rk * 64 + (((4 + h) ^ r7) * 8));
        bf16x8 ka3 = *(const bf16x8*)(KTc + rk * 64 + (((6 + h) ^ r7) * 8));
        f32x16 s;
        s = __builtin_amdgcn_mfma_f32_32x32x16_bf16(ka0, qb[0], z16, 0, 0, 0);
        s = __builtin_amdgcn_mfma_f32_32x32x16_bf16(ka1, qb[1], s, 0, 0, 0);
        s = __builtin_amdgcn_mfma_f32_32x32x16_bf16(ka2, qb[2], s, 0, 0, 0);
        s = __builtin_amdgcn_mfma_f32_32x32x16_bf16(ka3, qb[3], s, 0, 0, 0);

        // p = exp2(s - m); per-lane psum
        float p[16];
        float ps = 0.f;
        #pragma unroll
        for (int r = 0; r < 16; ++r) {
            p[r] = exp2f(s[r] - m);
            ps += p[r];
        }
        psum += ps;

        // P^T -> per-wave LDS (no XOR; stride-20-word rotation is conflict-free)
        // regs 4u..4u+3 -> keys_local 8u+4h+0..3 -> word 20*q5 + 4u + 2h
        #pragma unroll
        for (int u = 0; u < 4; ++u) {
            uint2 dd = { pk2(p[4 * u + 0], p[4 * u + 1]),
                         pk2(p[4 * u + 2], p[4 * u + 3]) };
            *(uint2*)(pwRow + u * 8 + 4 * h) = dd;
        }
        // B-frag read: n=q5, k-chunk = 2*s2 + h
        bf16x8 pb0 = *(const bf16x8*)(pwRow + (0 + h) * 8);
        bf16x8 pb1 = *(const bf16x8*)(pwRow + (2 + h) * 8);

        // PV: O^T[d][q] += V^T . P^T  (this wave's 32-key half)
        {
            bf16x8 va0 = *(const bf16x8*)(VSc + q5 * 64 + ((vc0 ^ r7) * 8));
            bf16x8 va1 = *(const bf16x8*)(VSc + q5 * 64 + ((vc1 ^ r7) * 8));
            o0 = __builtin_amdgcn_mfma_f32_32x32x16_bf16(va0, pb0, o0, 0, 0, 0);
            o0 = __builtin_amdgcn_mfma_f32_32x32x16_bf16(va1, pb1, o0, 0, 0, 0);
        }
        {
            bf16x8 va0 = *(const bf16x8*)(VSc + (32 + q5) * 64 + ((vc0 ^ r7) * 8));
            bf16x8 va1 = *(const bf16x8*)(VSc + (32 + q5) * 64 + ((vc1 ^ r7) * 8));
            o1 = __builtin_amdgcn_mfma_f32_32x32x16_bf16(va0, pb0, o1, 0, 0, 0);
            o1 = __builtin_amdgcn_mfma_f32_32x32x16_bf16(va1, pb1, o1, 0, 0, 0);
        }

        if (hasn) {
            #pragma unroll
            for (int h2 = 0; h2 < 2; ++h2) {
                int row = h2 * 32 + rr;
                *(u32x4*)(KTn + row * 64 + sw) = knx[h2];
                *(u32x4*)(VSn + row * 64 + sw) = vnx[h2];
            }
        }
        __syncthreads();
    }

    // ---- epilogue: merge key-halves, normalize, coalesced store ----
    float psq = psum + __shfl_xor(psum, 32);

    float* const Fsh = (float*)smem;                    // [2 qs][64 lanes][33]
    float* const LsF = (float*)(smem + 16896);          // [2 qs][64 lanes]
    u16*  const Osh = (u16*)(smem + 18432);             // [64 q][72]

    if (kh == 1) {
        float* fp = Fsh + (qs * 64 + l) * 33;
        #pragma unroll
        for (int r = 0; r < 16; ++r) { fp[r] = o0[r]; fp[16 + r] = o1[r]; }
        fp[32] = psq;
        LsF[qs * 64 + l] = psq;
    }
    __syncthreads();
    if (kh == 0) {
        const float* fp = Fsh + (qs * 64 + l) * 33;
        float inv = 1.0f / (psq + LsF[qs * 64 + l]);
        const int qloc = qs * 32 + q5;
        #pragma unroll
        for (int u = 0; u < 4; ++u) {
            uint2 b0 = { pk2((o0[4*u+0] + fp[4*u+0]) * inv, (o0[4*u+1] + fp[4*u+1]) * inv),
                         pk2((o0[4*u+2] + fp[4*u+2]) * inv, (o0[4*u+3] + fp[4*u+3]) * inv) };
            *(uint2*)(Osh + qloc * 72 + 8 * u + 4 * h) = b0;
            uint2 b1 = { pk2((o1[4*u+0] + fp[16+4*u+0]) * inv, (o1[4*u+1] + fp[16+4*u+1]) * inv),
                         pk2((o1[4*u+2] + fp[16+4*u+2]) * inv, (o1[4*u+3] + fp[16+4*u+3]) * inv) };
            *(uint2*)(Osh + qloc * 72 + 32 + 8 * u + 4 * h) = b1;
        }
    }
    __syncthreads();
    {   // coalesced copy Osh -> Att
        int row = t >> 2, cb = (t & 3) * 16;
        u16* dst = Att + ((size_t)(g * 2048 + qt * 64 + row)) * 64 + cb;
        *(u32x4*)(dst)     = *(const u32x4*)(Osh + row * 72 + cb);
        *(u32x4*)(dst + 8) = *(const u32x4*)(Osh + row * 72 + cb + 8);
    }
}

// ---------------------------------------------------------------------------
// Kernel 3: out = Att @ Wb^T + bfc (Wb bf16).  Double-buffered coalesced LDS
// staging, XOR-swizzled fragment reads.  BM=64, BN=64, BK=64; grid (64,8).
// ---------------------------------------------------------------------------
__global__ __launch_bounds__(256) void fc_kernel(
    const u16* __restrict__ Att, const u16* __restrict__ Wb,
    const float* __restrict__ bfc, float* __restrict__ out)
{
    __shared__ alignas(16) u16 Ash[2][64 * 64];
    __shared__ alignas(16) u16 Wsh[2][64 * 64];

    const int t = threadIdx.x, w = t >> 6, l = t & 63;
    const int r16 = l & 15, q4 = l >> 4;
    const int r7 = r16 & 7;
    const int m0 = blockIdx.x * 64, n0 = blockIdx.y * 64;

    const int rr = t >> 3, ck = t & 7;
    const int sw0 = (ck ^ (rr & 7)) * 8;
    const int fr0 = (q4 ^ r7) * 8;
    const int fr1 = ((q4 + 4) ^ r7) * 8;

    {
        #pragma unroll
        for (int h = 0; h < 2; ++h) {
            int row = h * 32 + rr;
            *(u32x4*)(&Ash[0][row * 64 + sw0]) = *(const u32x4*)(Att + (size_t)(m0 + row) * 512 + ck * 8);
            *(u32x4*)(&Wsh[0][row * 64 + sw0]) = *(const u32x4*)(Wb + (size_t)(n0 + row) * 512 + ck * 8);
        }
    }
    __syncthreads();

    f32x4 acc[4];
    const f32x4 zero = {0.f, 0.f, 0.f, 0.f};
    #pragma unroll
    for (int nc = 0; nc < 4; ++nc) acc[nc] = zero;

    for (int it = 0; it < 8; ++it) {
        const int cur = it & 1;
        const bool hasn = (it < 7);

        u32x4 anx[2], wnx[2];
        if (hasn) {
            #pragma unroll
            for (int h = 0; h < 2; ++h) {
                int row = h * 32 + rr;
                anx[h] = *(const u32x4*)(Att + (size_t)(m0 + row) * 512 + (it + 1) * 64 + ck * 8);
                wnx[h] = *(const u32x4*)(Wb + (size_t)(n0 + row) * 512 + (it + 1) * 64 + ck * 8);
            }
        }

        bf16x8 af[2], wf[4][2];
        af[0] = *(const bf16x8*)(&Ash[cur][(w * 16 + r16) * 64 + fr0]);
        af[1] = *(const bf16x8*)(&Ash[cur][(w * 16 + r16) * 64 + fr1]);
        #pragma unroll
        for (int nc = 0; nc < 4; ++nc) {
            wf[nc][0] = *(const bf16x8*)(&Wsh[cur][(nc * 16 + r16) * 64 + fr0]);
            wf[nc][1] = *(const bf16x8*)(&Wsh[cur][(nc * 16 + r16) * 64 + fr1]);
        }

        #pragma unroll
        for (int nc = 0; nc < 4; ++nc) {
            acc[nc] = __builtin_amdgcn_mfma_f32_16x16x32_bf16(af[0], wf[nc][0], acc[nc], 0, 0, 0);
            acc[nc] = __builtin_amdgcn_mfma_f32_16x16x32_bf16(af[1], wf[nc][1], acc[nc], 0, 0, 0);
        }

        if (hasn) {
            const int nxt = cur ^ 1;
            #pragma unroll
            for (int h = 0; h < 2; ++h) {
                int row = h * 32 + rr;
                *(u32x4*)(&Ash[nxt][row * 64 + sw0]) = anx[h];
                *(u32x4*)(&Wsh[nxt][row * 64 + sw0]) = wnx[h];
            }
        }
        __syncthreads();
    }

    #pragma unroll
    for (int nc = 0; nc < 4; ++nc) {
        float bb = bfc[n0 + nc * 16 + r16];
        #pragma unroll
        for (int r = 0; r < 4; ++r) {
            int row = m0 + w * 16 + q4 * 4 + r;
            out[(size_t)row * 512 + n0 + nc * 16 + r16] = acc[nc][r] + bb;
        }
    }
}

extern "C" void kernel_launch(void* const* d_in, const int* in_sizes, int n_in,
                              void* d_out, int out_size, void* d_ws, size_t ws_size,
                              hipStream_t stream) {
    (void)in_sizes; (void)n_in; (void)out_size; (void)ws_size;
    const float* q   = (const float*)d_in[0];
    const float* k   = (const float*)d_in[1];
    const float* v   = (const float*)d_in[2];
    const float* Wq  = (const float*)d_in[3];
    const float* Wk  = (const float*)d_in[4];
    const float* Wv  = (const float*)d_in[5];
    const float* Wfc = (const float*)d_in[6];
    const float* bfc = (const float*)d_in[7];
    float* out = (float*)d_out;

    u16* Qb = (u16*)d_ws;
    u16* Kb = Qb + 2097152;
    u16* Vt = Kb + 2097152;
    u16* At = Vt + 2097152;
    u16* Wb = At + 2097152;
    float* KnSq = (float*)((char*)d_ws + 17301504);

    proj_kernel<<<dim3(256, 1, 4), 256, 0, stream>>>(q, k, v, Wq, Wk, Wv, Wfc,
                                                     Qb, Kb, Vt, Wb, KnSq);
    flash_kernel<<<dim3(512), 256, 0, stream>>>(Qb, Kb, Vt, KnSq, At);
    fc_kernel<<<dim3(64, 8), 256, 0, stream>>>(At, Wb, bfc, out);
}

// Round 11
// 128.173 us; speedup vs baseline: 1.1061x; 1.0787x over previous
//
#include <hip/hip_runtime.h>
#include <hip/hip_bf16.h>

// MultiHeadAttention: S=2048, B=2, EMB=512, H=8, D=64 -> 16 (b,h) groups of
// [2048 x 64] attention + per-head 64x64 QKV proj + 512x512 output FC.
//
// R11: barrier-free flash on pre-swizzled fragment layouts. proj writes
// Q/K/V in MFMA-fragment order ([tile][role][kstep][lane][8]) so flash's
// fragment loads are lane-linear coalesced global b128 (L2/XCD-local).
// No K/V LDS, no in-loop __syncthreads; per-wave P round-trip only.
// C=-m folded into QK accumulator; row-sum l via all-ones A-frag MFMA.
//
// ws: [0)   Qf [g][qt 32][qs 2][s 4][lane 64][8] bf16 (Q pre-scaled 0.125*log2e)
//     [4M)  Kf [g][it 32][kh 2][s 4][lane 64][8] bf16
//     [8M)  Vf [g][it 32][kh 2][dc 2][s2 2][lane 64][8] bf16
//     [12M) At 32768x64 bf16
//     [16M) Wb 512x512 bf16
//     [16M+512K) KnSq[256] float

typedef __attribute__((ext_vector_type(8))) __bf16 bf16x8;
typedef __attribute__((ext_vector_type(4))) float f32x4;
typedef __attribute__((ext_vector_type(16))) float f32x16;
typedef __attribute__((ext_vector_type(4))) unsigned short u16x4;
typedef __attribute__((ext_vector_type(4))) unsigned int u32x4;
typedef unsigned short u16;
typedef unsigned int u32;

static __device__ __forceinline__ u16 f2bf(float x) {
    u32 u = __float_as_uint(x);
    u += 0x7fff + ((u >> 16) & 1);   // RNE
    return (u16)(u >> 16);
}
static __device__ __forceinline__ float bf2f(u16 h) {
    return __uint_as_float(((u32)h) << 16);
}
// packed bf16x2 convert (v_cvt_pk_bf16_f32 on gfx950)
static __device__ __forceinline__ u32 pk2(float lo, float hi) {
    __hip_bfloat162 h2 = __float22bfloat162_rn(make_float2(lo, hi));
    u32 r; __builtin_memcpy(&r, &h2, 4); return r;
}

// ---------------------------------------------------------------------------
// Kernel 1: z=0/1/2 -> QKV projection (Y = X@W^T * scale) written in
// MFMA-fragment order; z=3 -> Wfc->bf16.  z=1 also writes KnSq[bx].
// ---------------------------------------------------------------------------
__global__ __launch_bounds__(256) void proj_kernel(
    const float* __restrict__ q, const float* __restrict__ k, const float* __restrict__ v,
    const float* __restrict__ Wq, const float* __restrict__ Wk, const float* __restrict__ Wv,
    const float* __restrict__ Wfc,
    u16* __restrict__ Qf, u16* __restrict__ Kf, u16* __restrict__ Vf,
    u16* __restrict__ Wb, float* __restrict__ KnSq)
{
    const int mode = blockIdx.z;
    const int t = threadIdx.x;

    if (mode == 3) {
        int i = (blockIdx.x * 256 + t) * 4;
        float4 val = *(const float4*)(Wfc + i);
        uint2 b = { pk2(val.x, val.y), pk2(val.z, val.w) };
        *(uint2*)(Wb + i) = b;
        return;
    }

    const float* A = (mode == 0) ? q : (mode == 1) ? k : v;
    const float* W = (mode == 0) ? Wq : (mode == 1) ? Wk : Wv;
    const float osc = (mode == 0) ? 0.18033688011112042f : 1.0f; // 0.125*log2(e)

    __shared__ alignas(16) u16 Ash[128 * 88];   // input stage; reused as output stage
    __shared__ alignas(16) u16 Wsh[64 * 88];
    __shared__ float red[128];

    const int m0 = blockIdx.x * 128;
    const int w = t >> 6, l = t & 63;
    const int r16 = l & 15, q4 = l >> 4;

    {   // stage inputs (coalesced float4, pk-convert)
        const float4* A4 = (const float4*)(A + (size_t)m0 * 64);
        const int c4 = t & 15;
        #pragma unroll
        for (int i = 0; i < 8; ++i) {
            int row = (t >> 4) + i * 16;
            float4 val = A4[row * 16 + c4];
            uint2 bb = { pk2(val.x, val.y), pk2(val.z, val.w) };
            *(uint2*)(Ash + row * 88 + c4 * 4) = bb;
        }
        const float4* W4 = (const float4*)W;
        #pragma unroll
        for (int i = 0; i < 4; ++i) {
            int row = (t >> 4) + i * 16;
            float4 val = W4[row * 16 + c4];
            uint2 bb = { pk2(val.x, val.y), pk2(val.z, val.w) };
            *(uint2*)(Wsh + row * 88 + c4 * 4) = bb;
        }
    }
    __syncthreads();

    bf16x8 af[2][2], wf[4][2];
    #pragma unroll
    for (int mc = 0; mc < 2; ++mc)
        #pragma unroll
        for (int kk = 0; kk < 2; ++kk)
            af[mc][kk] = *(const bf16x8*)(Ash + (w * 32 + mc * 16 + r16) * 88 + kk * 32 + q4 * 8);
    #pragma unroll
    for (int nc = 0; nc < 4; ++nc)
        #pragma unroll
        for (int kk = 0; kk < 2; ++kk)
            wf[nc][kk] = *(const bf16x8*)(Wsh + (nc * 16 + r16) * 88 + kk * 32 + q4 * 8);

    f32x4 acc[2][4];
    const f32x4 zero = {0.f, 0.f, 0.f, 0.f};
    #pragma unroll
    for (int mc = 0; mc < 2; ++mc)
        #pragma unroll
        for (int nc = 0; nc < 4; ++nc) {
            acc[mc][nc] = __builtin_amdgcn_mfma_f32_16x16x32_bf16(af[mc][0], wf[nc][0], zero, 0, 0, 0);
            acc[mc][nc] = __builtin_amdgcn_mfma_f32_16x16x32_bf16(af[mc][1], wf[nc][1], acc[mc][nc], 0, 0, 0);
        }

    __syncthreads();   // done with input stage; reuse Ash

    const int g = m0 >> 11, t0 = (m0 & 2047) >> 6;   // group, first 64-tile

    // C/D layout: col(n) = lane&15, row(m) = quad*4 + reg
    if (mode < 2) {
        // store Y [128 rows][64] (scaled) into Ash with 72-stride
        #pragma unroll
        for (int mc = 0; mc < 2; ++mc)
            #pragma unroll
            for (int nc = 0; nc < 4; ++nc)
                #pragma unroll
                for (int r = 0; r < 4; ++r)
                    Ash[(w * 32 + mc * 16 + q4 * 4 + r) * 72 + nc * 16 + r16] = f2bf(acc[mc][nc][r] * osc);
        __syncthreads();
        // emit fragment order: [tile t0+tl][c2 (qs|kh)][s][lane][8]
        u16* Out = (mode == 0) ? Qf : Kf;
        #pragma unroll
        for (int i = 0; i < 4; ++i) {
            int idx = i * 256 + t;                 // [0,1024)
            int ll = idx & 63;
            int r = idx >> 6;                      // [0,16)
            int tl = r >> 3, c2 = (r >> 2) & 1, s = r & 3;
            int row = tl * 64 + c2 * 32 + (ll & 31);
            int col = s * 16 + (ll >> 5) * 8;
            u32x4 d = *(const u32x4*)(Ash + row * 72 + col);
            *(u32x4*)(Out + ((size_t)(((g * 32 + t0 + tl) * 2 + c2) * 4 + s) * 64 + ll) * 8) = d;
        }
        if (mode == 1) {   // per-block max ||K row||^2
            if (t < 128) {
                float ss = 0.f;
                #pragma unroll
                for (int c = 0; c < 8; ++c) {
                    u32x4 d = *(const u32x4*)(Ash + t * 72 + c * 8);
                    #pragma unroll
                    for (int j = 0; j < 4; ++j) {
                        float lo = bf2f((u16)(d[j] & 0xffff));
                        float hi = bf2f((u16)(d[j] >> 16));
                        ss += lo * lo + hi * hi;
                    }
                }
                red[t] = ss;
            }
            __syncthreads();
            if (t < 64) red[t] = fmaxf(red[t], red[t + 64]);
            __syncthreads();
            if (t < 32) red[t] = fmaxf(red[t], red[t + 32]);
            __syncthreads();
            if (t == 0) {
                float mx = red[0];
                for (int i = 1; i < 32; ++i) mx = fmaxf(mx, red[i]);
                KnSq[blockIdx.x] = mx;
            }
        }
    } else {
        // store V^T [64 d][128 keys] into Ash with 136-stride
        #pragma unroll
        for (int mc = 0; mc < 2; ++mc)
            #pragma unroll
            for (int nc = 0; nc < 4; ++nc)
                #pragma unroll
                for (int r = 0; r < 4; ++r)
                    Ash[(nc * 16 + r16) * 136 + w * 32 + mc * 16 + q4 * 4 + r] = f2bf(acc[mc][nc][r]);
        __syncthreads();
        // emit fragment order: [tile][kh][dc][s2][lane][8]
        #pragma unroll
        for (int i = 0; i < 4; ++i) {
            int idx = i * 256 + t;
            int ll = idx & 63;
            int r = idx >> 6;                       // [0,16)
            int tl = r >> 3, kh = (r >> 2) & 1, dc = (r >> 1) & 1, s2 = r & 1;
            int d = dc * 32 + (ll & 31);
            int keycol = tl * 64 + kh * 32 + s2 * 16 + (ll >> 5) * 8;
            u32x4 val = *(const u32x4*)(Ash + d * 136 + keycol);
            *(u32x4*)(Vf + ((size_t)((((g * 32 + t0 + tl) * 2 + kh) * 2 + dc) * 2 + s2) * 64 + ll) * 8) = val;
        }
    }
}

// ---------------------------------------------------------------------------
// Kernel 2: barrier-free flash on 32x32x16 MFMA.
// Block = 4 waves = (qs x kh); 64 q x 2048 keys; fragments loaded straight
// from Qf/Kf/Vf (lane-linear coalesced), depth-1 register prefetch.
// C=-m folded into QK accumulator; l-sum via all-ones A-frag MFMA.
// Per-wave P buffer [32 q][40 u16] (stride-20-word rotation, R10-verified).
// ---------------------------------------------------------------------------
__global__ __launch_bounds__(256) void flash_kernel(
    const u16* __restrict__ Qf, const u16* __restrict__ Kf,
    const u16* __restrict__ Vf, const float* __restrict__ KnSq,
    u16* __restrict__ Att)
{
    const int bi = blockIdx.x;
    const int g = bi & 15;        // XCD co-location (bi%8 == g%8)
    const int qt = bi >> 4;       // 0..31
    const int t = threadIdx.x, w = t >> 6, l = t & 63;
    const int q5 = l & 31, h = l >> 5;
    const int qs = w >> 1, kh = w & 1;

    // loop: per-wave P at [w*2560, +2560) bytes (total 10240).
    // epilogue overlay: Fsh [0,16896) LsF [16896,17408) Osh [17408,26624).
    __shared__ alignas(16) unsigned char smem[26624];
    u16* const pwRow = (u16*)smem + w * 1280 + q5 * 40;

    // fragment bases (u16 units); per-iteration stride 4096 (= 2*4*512)
    const u16* qbase = Qf + ((size_t)(((g * 32 + qt) * 2 + qs) * 4)) * 512 + l * 8;
    const u16* kbase = Kf + ((size_t)((g * 32 * 2 + kh) * 4)) * 512 + l * 8;
    const u16* vbase = Vf + ((size_t)((g * 32 * 2 + kh) * 4)) * 512 + l * 8;

    bf16x8 qb[4];
    #pragma unroll
    for (int s = 0; s < 4; ++s) qb[s] = *(const bf16x8*)(qbase + s * 512);

    // fixed bound m = ||Qrow_scaled|| * max||K|| * margin
    float m;
    {
        float kss = KnSq[g * 16 + (l & 15)];
        kss = fmaxf(kss, __shfl_xor(kss, 1));
        kss = fmaxf(kss, __shfl_xor(kss, 2));
        kss = fmaxf(kss, __shfl_xor(kss, 4));
        kss = fmaxf(kss, __shfl_xor(kss, 8));
        float ss = 0.f;
        #pragma unroll
        for (int s = 0; s < 4; ++s)
            #pragma unroll
            for (int j = 0; j < 8; ++j) {
                float x = (float)qb[s][j];
                ss += x * x;
            }
        ss += __shfl_xor(ss, 32);
        m = sqrtf(ss * kss) * 1.0002f;
    }

    f32x16 mC, o0, o1, ol;
    #pragma unroll
    for (int r = 0; r < 16; ++r) { mC[r] = -m; o0[r] = 0.f; o1[r] = 0.f; ol[r] = 0.f; }

    const u16 one_bf = 0x3F80;
    bf16x8 ones;
    #pragma unroll
    for (int j = 0; j < 8; ++j) ones[j] = ((const __bf16*)&one_bf)[0];

    // prefetch tile 0
    bf16x8 ka[4], va[4], kan[4], van[4];
    #pragma unroll
    for (int s = 0; s < 4; ++s) ka[s] = *(const bf16x8*)(kbase + s * 512);
    #pragma unroll
    for (int j = 0; j < 4; ++j) va[j] = *(const bf16x8*)(vbase + j * 512);

    for (int it = 0; it < 32; ++it) {
        const size_t nx = (size_t)((it + 1) & 31) * 4096;
        #pragma unroll
        for (int s = 0; s < 4; ++s) kan[s] = *(const bf16x8*)(kbase + nx + s * 512);
        #pragma unroll
        for (int j = 0; j < 4; ++j) van[j] = *(const bf16x8*)(vbase + nx + j * 512);

        // S^T = K.Q^T - m  (C operand = -m)
        f32x16 s;
        s = __builtin_amdgcn_mfma_f32_32x32x16_bf16(ka[0], qb[0], mC, 0, 0, 0);
        s = __builtin_amdgcn_mfma_f32_32x32x16_bf16(ka[1], qb[1], s, 0, 0, 0);
        s = __builtin_amdgcn_mfma_f32_32x32x16_bf16(ka[2], qb[2], s, 0, 0, 0);
        s = __builtin_amdgcn_mfma_f32_32x32x16_bf16(ka[3], qb[3], s, 0, 0, 0);

        // p = exp2(s)  (already shifted)
        float p[16];
        #pragma unroll
        for (int r = 0; r < 16; ++r) p[r] = exp2f(s[r]);

        // P^T -> per-wave LDS (regs 4u.. -> keys 8u+4h+..), then B-frags
        #pragma unroll
        for (int u = 0; u < 4; ++u) {
            uint2 dd = { pk2(p[4 * u + 0], p[4 * u + 1]),
                         pk2(p[4 * u + 2], p[4 * u + 3]) };
            *(uint2*)(pwRow + u * 8 + 4 * h) = dd;
        }
        bf16x8 pb0 = *(const bf16x8*)(pwRow + (0 + h) * 8);
        bf16x8 pb1 = *(const bf16x8*)(pwRow + (2 + h) * 8);

        // PV + l-sum (ones row)
        o0 = __builtin_amdgcn_mfma_f32_32x32x16_bf16(va[0], pb0, o0, 0, 0, 0);
        o0 = __builtin_amdgcn_mfma_f32_32x32x16_bf16(va[1], pb1, o0, 0, 0, 0);
        o1 = __builtin_amdgcn_mfma_f32_32x32x16_bf16(va[2], pb0, o1, 0, 0, 0);
        o1 = __builtin_amdgcn_mfma_f32_32x32x16_bf16(va[3], pb1, o1, 0, 0, 0);
        ol = __builtin_amdgcn_mfma_f32_32x32x16_bf16(ones, pb0, ol, 0, 0, 0);
        ol = __builtin_amdgcn_mfma_f32_32x32x16_bf16(ones, pb1, ol, 0, 0, 0);

        #pragma unroll
        for (int s2 = 0; s2 < 4; ++s2) { ka[s2] = kan[s2]; va[s2] = van[s2]; }
    }

    // ---- epilogue: merge key-halves, normalize, coalesced store ----
    float psq = ol[0];                                  // l_half[q5], all lanes

    float* const Fsh = (float*)smem;                    // [2 qs][64 lanes][33]
    float* const LsF = (float*)(smem + 16896);          // [2 qs][64 lanes]
    u16*  const Osh = (u16*)(smem + 17408);             // [64 q][72]

    __syncthreads();   // all waves done with P region before overlay reuse
    if (kh == 1) {
        float* fp = Fsh + (qs * 64 + l) * 33;
        #pragma unroll
        for (int r = 0; r < 16; ++r) { fp[r] = o0[r]; fp[16 + r] = o1[r]; }
        fp[32] = psq;
        LsF[qs * 64 + l] = psq;
    }
    __syncthreads();
    if (kh == 0) {
        const float* fp = Fsh + (qs * 64 + l) * 33;
        float inv = 1.0f / (psq + LsF[qs * 64 + l]);
        const int qloc = qs * 32 + q5;
        #pragma unroll
        for (int u = 0; u < 4; ++u) {
            uint2 b0 = { pk2((o0[4*u+0] + fp[4*u+0]) * inv, (o0[4*u+1] + fp[4*u+1]) * inv),
                         pk2((o0[4*u+2] + fp[4*u+2]) * inv, (o0[4*u+3] + fp[4*u+3]) * inv) };
            *(uint2*)(Osh + qloc * 72 + 8 * u + 4 * h) = b0;
            uint2 b1 = { pk2((o1[4*u+0] + fp[16+4*u+0]) * inv, (o1[4*u+1] + fp[16+4*u+1]) * inv),
                         pk2((o1[4*u+2] + fp[16+4*u+2]) * inv, (o1[4*u+3] + fp[16+4*u+3]) * inv) };
            *(uint2*)(Osh + qloc * 72 + 32 + 8 * u + 4 * h) = b1;
        }
    }
    __syncthreads();
    {   // coalesced copy Osh -> Att
        int row = t >> 2, cb = (t & 3) * 16;
        u16* dst = Att + ((size_t)(g * 2048 + qt * 64 + row)) * 64 + cb;
        *(u32x4*)(dst)     = *(const u32x4*)(Osh + row * 72 + cb);
        *(u32x4*)(dst + 8) = *(const u32x4*)(Osh + row * 72 + cb + 8);
    }
}

// ---------------------------------------------------------------------------
// Kernel 3: out = Att @ Wb^T + bfc (Wb bf16).  Double-buffered coalesced LDS
// staging, XOR-swizzled fragment reads.  BM=64, BN=64, BK=64; grid (64,8).
// ---------------------------------------------------------------------------
__global__ __launch_bounds__(256) void fc_kernel(
    const u16* __restrict__ Att, const u16* __restrict__ Wb,
    const float* __restrict__ bfc, float* __restrict__ out)
{
    __shared__ alignas(16) u16 Ash[2][64 * 64];
    __shared__ alignas(16) u16 Wsh[2][64 * 64];

    const int t = threadIdx.x, w = t >> 6, l = t & 63;
    const int r16 = l & 15, q4 = l >> 4;
    const int r7 = r16 & 7;
    const int m0 = blockIdx.x * 64, n0 = blockIdx.y * 64;

    const int rr = t >> 3, ck = t & 7;
    const int sw0 = (ck ^ (rr & 7)) * 8;
    const int fr0 = (q4 ^ r7) * 8;
    const int fr1 = ((q4 + 4) ^ r7) * 8;

    {
        #pragma unroll
        for (int h = 0; h < 2; ++h) {
            int row = h * 32 + rr;
            *(u32x4*)(&Ash[0][row * 64 + sw0]) = *(const u32x4*)(Att + (size_t)(m0 + row) * 512 + ck * 8);
            *(u32x4*)(&Wsh[0][row * 64 + sw0]) = *(const u32x4*)(Wb + (size_t)(n0 + row) * 512 + ck * 8);
        }
    }
    __syncthreads();

    f32x4 acc[4];
    const f32x4 zero = {0.f, 0.f, 0.f, 0.f};
    #pragma unroll
    for (int nc = 0; nc < 4; ++nc) acc[nc] = zero;

    for (int it = 0; it < 8; ++it) {
        const int cur = it & 1;
        const bool hasn = (it < 7);

        u32x4 anx[2], wnx[2];
        if (hasn) {
            #pragma unroll
            for (int h = 0; h < 2; ++h) {
                int row = h * 32 + rr;
                anx[h] = *(const u32x4*)(Att + (size_t)(m0 + row) * 512 + (it + 1) * 64 + ck * 8);
                wnx[h] = *(const u32x4*)(Wb + (size_t)(n0 + row) * 512 + (it + 1) * 64 + ck * 8);
            }
        }

        bf16x8 af[2], wf[4][2];
        af[0] = *(const bf16x8*)(&Ash[cur][(w * 16 + r16) * 64 + fr0]);
        af[1] = *(const bf16x8*)(&Ash[cur][(w * 16 + r16) * 64 + fr1]);
        #pragma unroll
        for (int nc = 0; nc < 4; ++nc) {
            wf[nc][0] = *(const bf16x8*)(&Wsh[cur][(nc * 16 + r16) * 64 + fr0]);
            wf[nc][1] = *(const bf16x8*)(&Wsh[cur][(nc * 16 + r16) * 64 + fr1]);
        }

        #pragma unroll
        for (int nc = 0; nc < 4; ++nc) {
            acc[nc] = __builtin_amdgcn_mfma_f32_16x16x32_bf16(af[0], wf[nc][0], acc[nc], 0, 0, 0);
            acc[nc] = __builtin_amdgcn_mfma_f32_16x16x32_bf16(af[1], wf[nc][1], acc[nc], 0, 0, 0);
        }

        if (hasn) {
            const int nxt = cur ^ 1;
            #pragma unroll
            for (int h = 0; h < 2; ++h) {
                int row = h * 32 + rr;
                *(u32x4*)(&Ash[nxt][row * 64 + sw0]) = anx[h];
                *(u32x4*)(&Wsh[nxt][row * 64 + sw0]) = wnx[h];
            }
        }
        __syncthreads();
    }

    #pragma unroll
    for (int nc = 0; nc < 4; ++nc) {
        float bb = bfc[n0 + nc * 16 + r16];
        #pragma unroll
        for (int r = 0; r < 4; ++r) {
            int row = m0 + w * 16 + q4 * 4 + r;
            out[(size_t)row * 512 + n0 + nc * 16 + r16] = acc[nc][r] + bb;
        }
    }
}

extern "C" void kernel_launch(void* const* d_in, const int* in_sizes, int n_in,
                              void* d_out, int out_size, void* d_ws, size_t ws_size,
                              hipStream_t stream) {
    (void)in_sizes; (void)n_in; (void)out_size; (void)ws_size;
    const float* q   = (const float*)d_in[0];
    const float* k   = (const float*)d_in[1];
    const float* v   = (const float*)d_in[2];
    const float* Wq  = (const float*)d_in[3];
    const float* Wk  = (const float*)d_in[4];
    const float* Wv  = (const float*)d_in[5];
    const float* Wfc = (const float*)d_in[6];
    const float* bfc = (const float*)d_in[7];
    float* out = (float*)d_out;

    u16* Qf = (u16*)d_ws;
    u16* Kf = Qf + 2097152;
    u16* Vf = Kf + 2097152;
    u16* At = Vf + 2097152;
    u16* Wb = At + 2097152;
    float* KnSq = (float*)((char*)d_ws + 17301504);

    proj_kernel<<<dim3(256, 1, 4), 256, 0, stream>>>(q, k, v, Wq, Wk, Wv, Wfc,
                                                     Qf, Kf, Vf, Wb, KnSq);
    flash_kernel<<<dim3(512), 256, 0, stream>>>(Qf, Kf, Vf, KnSq, At);
    fc_kernel<<<dim3(64, 8), 256, 0, stream>>>(At, Wb, bfc, out);
}